// Round 1
// baseline (7511.646 us; speedup 1.0000x reference)
//
#include <hip/hip_runtime.h>
#include <math.h>

// Problem constants
#define NN 2048   // meta-nodes
#define MM 64     // subgraph nodes
#define DD 64     // channels
#define MD 4096   // MM*DD
#define NLAYER 3
#define EPS 1e-5f

// ---------------- elementwise int -> float ----------------
__global__ __launch_bounds__(256) void int2float_kernel(const int* __restrict__ a,
                                                        float* __restrict__ o, int n) {
    int i = blockIdx.x * 256 + threadIdx.x;
    if (i < n) o[i] = (float)a[i];
}

// ---------------- Sn = D^-1/2 (A+I) D^-1/2 (64x64) ----------------
__global__ __launch_bounds__(256) void sn_kernel(const int* __restrict__ sub,
                                                 float* __restrict__ Sn) {
    __shared__ float dinv[64];
    int tid = threadIdx.x;
    if (tid < 64) {
        float s = 1.f;  // self loop
        for (int v = 0; v < 64; ++v) s += (float)sub[tid * 64 + v];
        dinv[tid] = 1.f / sqrtf(s);
    }
    __syncthreads();
    for (int t = tid; t < 4096; t += 256) {
        int u = t >> 6, v = t & 63;
        float a = (float)sub[t] + (u == v ? 1.f : 0.f);
        Sn[t] = dinv[u] * a * dinv[v];
    }
}

// ---------------- generic fp32 GEMM: C = A(MxK) @ B(KxN) ----------------
// 64x64 block tile, 16x16 threads x (4x4 microtile), K-tile 16
#define TS 64
#define KT 16
__global__ __launch_bounds__(256) void gemm_f32(const float* __restrict__ A,
                                                const float* __restrict__ B,
                                                float* __restrict__ C,
                                                int Mdim, int Ndim, int Kdim) {
    __shared__ float As[KT][TS + 1];
    __shared__ float Bs[KT][TS + 1];
    const int bm = blockIdx.y * TS;
    const int bn = blockIdx.x * TS;
    const int tid = threadIdx.x;
    const int tx = tid & 15, ty = tid >> 4;
    float acc[4][4] = {};
    for (int k0 = 0; k0 < Kdim; k0 += KT) {
#pragma unroll
        for (int r = 0; r < 4; ++r) {
            int t = tid + r * 256;
            int m = t >> 4, k = t & 15;
            As[k][m] = A[(size_t)(bm + m) * Kdim + k0 + k];
            int k2 = t >> 6, n2 = t & 63;
            Bs[k2][n2] = B[(size_t)(k0 + k2) * Ndim + bn + n2];
        }
        __syncthreads();
#pragma unroll
        for (int k = 0; k < KT; ++k) {
            float a0 = As[k][ty * 4 + 0], a1 = As[k][ty * 4 + 1];
            float a2 = As[k][ty * 4 + 2], a3 = As[k][ty * 4 + 3];
            float b0 = Bs[k][tx * 4 + 0], b1 = Bs[k][tx * 4 + 1];
            float b2 = Bs[k][tx * 4 + 2], b3 = Bs[k][tx * 4 + 3];
            acc[0][0] += a0 * b0; acc[0][1] += a0 * b1; acc[0][2] += a0 * b2; acc[0][3] += a0 * b3;
            acc[1][0] += a1 * b0; acc[1][1] += a1 * b1; acc[1][2] += a1 * b2; acc[1][3] += a1 * b3;
            acc[2][0] += a2 * b0; acc[2][1] += a2 * b1; acc[2][2] += a2 * b2; acc[2][3] += a2 * b3;
            acc[3][0] += a3 * b0; acc[3][1] += a3 * b1; acc[3][2] += a3 * b2; acc[3][3] += a3 * b3;
        }
        __syncthreads();
    }
#pragma unroll
    for (int i = 0; i < 4; ++i)
#pragma unroll
        for (int j = 0; j < 4; ++j)
            C[(size_t)(bm + ty * 4 + i) * Ndim + bn + tx * 4 + j] = acc[i][j];
}

// ---------------- sub-GCN: H[n] (+)= Sn @ (Xin[n] @ W) + b ----------------
// one block per meta-node n
__global__ __launch_bounds__(256) void gcn_kernel(const float* __restrict__ Xin,
                                                  const float* __restrict__ W,
                                                  const float* __restrict__ bias,
                                                  const float* __restrict__ Sn,
                                                  float* __restrict__ H, int accum) {
    __shared__ float Xs[64][65];
    __shared__ float Ws[64][65];
    __shared__ float Ts[64][65];
    const int n = blockIdx.x;
    const int tid = threadIdx.x;
    const float* Xn = Xin + (size_t)n * MD;
    for (int t = tid; t < 4096; t += 256) {
        int r = t >> 6, c = t & 63;
        Xs[r][c] = Xn[t];
        Ws[r][c] = W[t];
    }
    __syncthreads();
    const int tx = tid & 15, ty = tid >> 4;
    // T = Xn @ W
    float acc[4][4] = {};
#pragma unroll 8
    for (int k = 0; k < 64; ++k) {
        float a0 = Xs[ty * 4 + 0][k], a1 = Xs[ty * 4 + 1][k];
        float a2 = Xs[ty * 4 + 2][k], a3 = Xs[ty * 4 + 3][k];
        float b0 = Ws[k][tx * 4 + 0], b1 = Ws[k][tx * 4 + 1];
        float b2 = Ws[k][tx * 4 + 2], b3 = Ws[k][tx * 4 + 3];
        acc[0][0] += a0 * b0; acc[0][1] += a0 * b1; acc[0][2] += a0 * b2; acc[0][3] += a0 * b3;
        acc[1][0] += a1 * b0; acc[1][1] += a1 * b1; acc[1][2] += a1 * b2; acc[1][3] += a1 * b3;
        acc[2][0] += a2 * b0; acc[2][1] += a2 * b1; acc[2][2] += a2 * b2; acc[2][3] += a2 * b3;
        acc[3][0] += a3 * b0; acc[3][1] += a3 * b1; acc[3][2] += a3 * b2; acc[3][3] += a3 * b3;
    }
#pragma unroll
    for (int i = 0; i < 4; ++i)
#pragma unroll
        for (int j = 0; j < 4; ++j) Ts[ty * 4 + i][tx * 4 + j] = acc[i][j];
    __syncthreads();
    // Z = Sn @ T  (Sn read through L1; rows broadcast within the wave)
    float acc2[4][4] = {};
#pragma unroll 8
    for (int v = 0; v < 64; ++v) {
        float a0 = Sn[(ty * 4 + 0) * 64 + v], a1 = Sn[(ty * 4 + 1) * 64 + v];
        float a2 = Sn[(ty * 4 + 2) * 64 + v], a3 = Sn[(ty * 4 + 3) * 64 + v];
        float b0 = Ts[v][tx * 4 + 0], b1 = Ts[v][tx * 4 + 1];
        float b2 = Ts[v][tx * 4 + 2], b3 = Ts[v][tx * 4 + 3];
        acc2[0][0] += a0 * b0; acc2[0][1] += a0 * b1; acc2[0][2] += a0 * b2; acc2[0][3] += a0 * b3;
        acc2[1][0] += a1 * b0; acc2[1][1] += a1 * b1; acc2[1][2] += a1 * b2; acc2[1][3] += a1 * b3;
        acc2[2][0] += a2 * b0; acc2[2][1] += a2 * b1; acc2[2][2] += a2 * b2; acc2[2][3] += a2 * b3;
        acc2[3][0] += a3 * b0; acc2[3][1] += a3 * b1; acc2[3][2] += a3 * b2; acc2[3][3] += a3 * b3;
    }
    float* Hn = H + (size_t)n * MD;
#pragma unroll
    for (int i = 0; i < 4; ++i)
#pragma unroll
        for (int j = 0; j < 4; ++j) {
            int idx = (ty * 4 + i) * 64 + tx * 4 + j;
            float val = acc2[i][j] + bias[tx * 4 + j];
            Hn[idx] = accum ? (Hn[idx] + val) : val;
        }
}

// ---------------- LayerNorm over (m,d) + ReLU ----------------
__global__ __launch_bounds__(256) void ln_relu_kernel(const float* __restrict__ H,
                                                      const float* __restrict__ gamma,
                                                      const float* __restrict__ beta,
                                                      float* __restrict__ X) {
    const int n = blockIdx.x;
    const int tid = threadIdx.x;
    const float* h = H + (size_t)n * MD;
    __shared__ float wsum[4], wsum2[4];
    float s = 0.f;
    for (int t = tid; t < MD; t += 256) s += h[t];
#pragma unroll
    for (int o = 32; o; o >>= 1) s += __shfl_down(s, o);
    if ((tid & 63) == 0) wsum[tid >> 6] = s;
    __syncthreads();
    float mean = (wsum[0] + wsum[1] + wsum[2] + wsum[3]) * (1.f / 4096.f);
    float v2 = 0.f;
    for (int t = tid; t < MD; t += 256) { float d = h[t] - mean; v2 += d * d; }
#pragma unroll
    for (int o = 32; o; o >>= 1) v2 += __shfl_down(v2, o);
    if ((tid & 63) == 0) wsum2[tid >> 6] = v2;
    __syncthreads();
    float var = (wsum2[0] + wsum2[1] + wsum2[2] + wsum2[3]) * (1.f / 4096.f);
    float rstd = 1.f / sqrtf(var + EPS);
    float* xo = X + (size_t)n * MD;
    for (int t = tid; t < MD; t += 256) {
        float val = (h[t] - mean) * rstd * gamma[t] + beta[t];
        xo[t] = val > 0.f ? val : 0.f;
    }
}

// ---------------- readout: out = X(N,4096) @ Wlin(4096,64) + blin ----------------
__global__ __launch_bounds__(256) void readout_kernel(const float* __restrict__ X,
                                                      const float* __restrict__ Wl,
                                                      const float* __restrict__ bl,
                                                      float* __restrict__ out) {
    const int n = blockIdx.x;
    const int o = threadIdx.x & 63, c = threadIdx.x >> 6;
    const float* xn = X + (size_t)n * MD;
    float s = 0.f;
    for (int i = c * 1024; i < (c + 1) * 1024; ++i) s += xn[i] * Wl[(size_t)i * 64 + o];
    __shared__ float red[4][64];
    red[c][o] = s;
    __syncthreads();
    if (c == 0) out[(size_t)n * 64 + o] = red[0][o] + red[1][o] + red[2][o] + red[3][o] + bl[o];
}

extern "C" void kernel_launch(void* const* d_in, const int* in_sizes, int n_in,
                              void* d_out, int out_size, void* d_ws, size_t ws_size,
                              hipStream_t stream) {
    const float* x     = (const float*)d_in[0];
    const int*   sub   = (const int*)d_in[1];
    const int*   adj   = (const int*)d_in[2];
    const float* Wc    = (const float*)d_in[3];
    const float* bc    = (const float*)d_in[4];
    const float* gamma = (const float*)d_in[5];
    const float* beta  = (const float*)d_in[6];
    const float* Wlin  = (const float*)d_in[7];
    const float* blin  = (const float*)d_in[8];
    float* out = (float*)d_out;

    float* ws = (float*)d_ws;
    float* Af = ws; ws += (size_t)NN * NN;
    float* A2 = ws; ws += (size_t)NN * NN;
    float* A3 = ws; ws += (size_t)NN * NN;
    float* Sn = ws; ws += 4096;
    float* X0 = ws; ws += (size_t)NN * MD;
    float* X1 = ws; ws += (size_t)NN * MD;
    float* H  = ws; ws += (size_t)NN * MD;

    const int nadj = NN * NN;
    int2float_kernel<<<(nadj + 255) / 256, 256, 0, stream>>>(adj, Af, nadj);
    sn_kernel<<<1, 256, 0, stream>>>(sub, Sn);

    dim3 gsq(NN / TS, NN / TS);           // 32x32
    gemm_f32<<<gsq, 256, 0, stream>>>(Af, Af, A2, NN, NN, NN);
    gemm_f32<<<gsq, 256, 0, stream>>>(A2, Af, A3, NN, NN, NN);

    const float* P[3] = {Af, A2, A3};
    dim3 gp(MD / TS, NN / TS);            // 64x32 (col blocks, row blocks)
    const float* xin = x;
    for (int l = 0; l < NLAYER; ++l) {
        const float* Wl = Wc + (size_t)l * 4 * 4096;
        const float* bl = bc + (size_t)l * 4 * 64;
        // h = gcn0(x)
        gcn_kernel<<<NN, 256, 0, stream>>>(xin, Wl, bl, Sn, H, 0);
        // x1 = A @ x ; h += gcn1(x1)
        gemm_f32<<<gp, 256, 0, stream>>>(P[0], xin, X1, NN, MD, NN);
        gcn_kernel<<<NN, 256, 0, stream>>>(X1, Wl + 4096, bl + 64, Sn, H, 1);
        // x2 = A2 @ x1 ; h += gcn2(x2)   (X0 safe to overwrite now)
        gemm_f32<<<gp, 256, 0, stream>>>(P[1], X1, X0, NN, MD, NN);
        gcn_kernel<<<NN, 256, 0, stream>>>(X0, Wl + 2 * 4096, bl + 2 * 64, Sn, H, 1);
        // x3 = A3 @ x2 ; h += gcn3(x3)
        gemm_f32<<<gp, 256, 0, stream>>>(P[2], X0, X1, NN, MD, NN);
        gcn_kernel<<<NN, 256, 0, stream>>>(X1, Wl + 3 * 4096, bl + 3 * 64, Sn, H, 1);
        // LayerNorm + ReLU -> X0 (next layer input)
        ln_relu_kernel<<<NN, 256, 0, stream>>>(H, gamma + (size_t)l * 4096,
                                               beta + (size_t)l * 4096, X0);
        xin = X0;
    }
    readout_kernel<<<NN, 256, 0, stream>>>(X0, Wlin, blin, out);
}

// Round 2
// 2169.835 us; speedup vs baseline: 3.4619x; 3.4619x over previous
//
#include <hip/hip_runtime.h>
#include <math.h>

// Problem constants
#define NN 2048   // meta-nodes
#define MM 64     // subgraph nodes
#define DD 64     // channels
#define MD 4096   // MM*DD
#define NLAYER 3
#define EPS 1e-5f

typedef unsigned short u16;
typedef unsigned int u32;
typedef __attribute__((ext_vector_type(8))) short bf16x8;
typedef __attribute__((ext_vector_type(4))) float f32x4;

__device__ inline u16 f32_to_bf16(float f) {
    u32 u = __float_as_uint(f);
    u32 r = (u + 0x7FFFu + ((u >> 16) & 1u)) >> 16;   // RNE
    return (u16)r;
}
__device__ inline float bf16_to_f32(u16 h) { return __uint_as_float((u32)h << 16); }

// ---------------- A prep: adj(int) -> A bf16 (row-major) + A^T bf16 ----------------
__global__ __launch_bounds__(256) void aprep_kernel(const int* __restrict__ adj,
                                                    u16* __restrict__ Abf,
                                                    u16* __restrict__ ATbf) {
    __shared__ u16 T[64][65];
    const int r0 = blockIdx.y * 64, c0 = blockIdx.x * 64;
    const int tid = threadIdx.x;
#pragma unroll
    for (int e = 0; e < 16; ++e) {
        int idx = e * 256 + tid;
        int i = idx >> 6, j = idx & 63;
        int a = adj[(long)(r0 + i) * NN + c0 + j];
        u16 b = a ? (u16)0x3F80 : (u16)0;
        Abf[(long)(r0 + i) * NN + c0 + j] = b;
        T[i][j] = b;
    }
    __syncthreads();
#pragma unroll
    for (int e = 0; e < 16; ++e) {
        int idx = e * 256 + tid;
        int cc = idx >> 6, rr = idx & 63;
        ATbf[(long)(c0 + cc) * NN + r0 + rr] = T[rr][cc];
    }
}

// ---------------- Sn = D^-1/2 (A+I) D^-1/2 (64x64) ----------------
__global__ __launch_bounds__(256) void sn_kernel(const int* __restrict__ sub,
                                                 float* __restrict__ Sn) {
    __shared__ float dinv[64];
    int tid = threadIdx.x;
    if (tid < 64) {
        float s = 1.f;  // self loop
        for (int v = 0; v < 64; ++v) s += (float)sub[tid * 64 + v];
        dinv[tid] = 1.f / sqrtf(s);
    }
    __syncthreads();
    for (int t = tid; t < 4096; t += 256) {
        int u = t >> 6, v = t & 63;
        float a = (float)sub[t] + (u == v ? 1.f : 0.f);
        Sn[t] = dinv[u] * a * dinv[v];
    }
}

// ---------------- split fp32 -> S bf16 planes, row-major (for A-powers) ----------------
template <int S>
__global__ __launch_bounds__(256) void split_pow_kernel(const float* __restrict__ X,
                                                        u16* __restrict__ P, long n) {
    long i = (long)blockIdx.x * 256 + threadIdx.x;
    if (i >= n) return;
    float v = X[i];
#pragma unroll
    for (int s = 0; s < S; ++s) {
        u16 h = f32_to_bf16(v);
        P[(long)s * n + i] = h;
        v -= bf16_to_f32(h);
    }
}

// ---------------- split fp32 X[R][C] -> 3 bf16 planes transposed [C][R] ----------------
__global__ __launch_bounds__(256) void split3t_kernel(const float* __restrict__ X,
                                                      u16* __restrict__ P, int R, int Cc) {
    __shared__ float T[64][65];
    const int r0 = blockIdx.y * 64, c0 = blockIdx.x * 64;
    const int tid = threadIdx.x;
#pragma unroll
    for (int e = 0; e < 16; ++e) {
        int idx = e * 256 + tid;
        int i = idx >> 6, j = idx & 63;
        T[i][j] = X[(long)(r0 + i) * Cc + c0 + j];
    }
    __syncthreads();
    const long planeStride = (long)R * Cc;
#pragma unroll
    for (int e = 0; e < 16; ++e) {
        int idx = e * 256 + tid;
        int cc = idx >> 6, rr = idx & 63;  // consecutive rr -> coalesced writes
        float v = T[rr][cc];
        u16 h = f32_to_bf16(v);
        float r1 = v - bf16_to_f32(h);
        u16 lo = f32_to_bf16(r1);
        float r2 = r1 - bf16_to_f32(lo);
        u16 ll = f32_to_bf16(r2);
        long o = (long)(c0 + cc) * R + r0 + rr;
        P[o] = h;
        P[planeStride + o] = lo;
        P[2 * planeStride + o] = ll;
    }
}

// ---------------- multi-split-pair MFMA GEMM ----------------
// C[m][n] = sum_{s<SP, t<SQ, s+t<=SMAX} Ap[s][m][k] * Bp[t][n][k]
// Ap planes row-major [M][K]; Bp planes row-major [N][K] (i.e. B^T).
// BM=BN=128, BK=32, 256 threads = 4 waves (2x2), wave tile 64x64.
// LDS tiles 128x32 bf16, XOR-swizzled on 16B units: u_store = u ^ ((u>>3)&7).
template <int SP, int SQ, int SMAX>
__global__ __launch_bounds__(256) void gemm_pairs(const u16* __restrict__ Ap, long aStride,
                                                  const u16* __restrict__ Bp, long bStride,
                                                  float* __restrict__ C, int M, int N, int K) {
    __shared__ u16 lds[(SP + SQ) * 4096];
    const int tid = threadIdx.x;
    const int wave = tid >> 6, lane = tid & 63;
    const int bm = blockIdx.y * 128, bn = blockIdx.x * 128;
    const int wr = (wave >> 1) * 64, wc = (wave & 1) * 64;

    f32x4 acc[4][4];
#pragma unroll
    for (int i = 0; i < 4; ++i)
#pragma unroll
        for (int j = 0; j < 4; ++j) acc[i][j] = (f32x4){0.f, 0.f, 0.f, 0.f};

    // frag read byte offsets within a plane-tile (swizzled)
    const int kb16 = lane >> 4, lr = lane & 15;
    int aoff[4], boff[4];
#pragma unroll
    for (int mi = 0; mi < 4; ++mi) {
        int ua = (wr + mi * 16 + lr) * 4 + kb16;
        aoff[mi] = (ua ^ ((ua >> 3) & 7)) * 16;
        int ub = (wc + mi * 16 + lr) * 4 + kb16;
        boff[mi] = (ub ^ ((ub >> 3) & 7)) * 16;
    }
    // staging decode: issue uu covers store-units [i*64, i*64+63]; lane l holds unit i*64+l.
    // logical unit = store-unit ^ ((store>>3)&7)  (self-inverse, bits 0-2 only)
    for (int k0 = 0; k0 < K; k0 += 32) {
#pragma unroll
        for (int u8 = 0; u8 < (SP + SQ) * 2; ++u8) {
            int uu = u8 * 4 + wave;           // wave-uniform issue id
            int p = uu >> 3, i = uu & 7;
            int us = i * 64 + lane;
            int ulin = us ^ ((us >> 3) & 7);
            int r = ulin >> 2, kb = ulin & 3;
            const u16* src;
            int rowbase;
            if (p < SP) { src = Ap + (long)p * aStride; rowbase = bm; }
            else        { src = Bp + (long)(p - SP) * bStride; rowbase = bn; }
            const char* g = (const char*)src + ((long)(rowbase + r) * K + k0) * 2 + kb * 16;
            char* l = (char*)lds + p * 8192 + i * 1024 + lane * 16;
            __builtin_amdgcn_global_load_lds((const __attribute__((address_space(1))) void*)g,
                                             (__attribute__((address_space(3))) void*)l, 16, 0, 0);
        }
        __syncthreads();
        bf16x8 a[SP][4], b[SQ][4];
#pragma unroll
        for (int s = 0; s < SP; ++s)
#pragma unroll
            for (int mi = 0; mi < 4; ++mi)
                a[s][mi] = *(const bf16x8*)((const char*)lds + s * 8192 + aoff[mi]);
#pragma unroll
        for (int t = 0; t < SQ; ++t)
#pragma unroll
            for (int ni = 0; ni < 4; ++ni)
                b[t][ni] = *(const bf16x8*)((const char*)lds + (SP + t) * 8192 + boff[ni]);
#pragma unroll
        for (int s = 0; s < SP; ++s)
#pragma unroll
            for (int t = 0; t < SQ; ++t)
                if (s + t <= SMAX) {
#pragma unroll
                    for (int mi = 0; mi < 4; ++mi)
#pragma unroll
                        for (int ni = 0; ni < 4; ++ni)
                            acc[mi][ni] = __builtin_amdgcn_mfma_f32_16x16x32_bf16(
                                a[s][mi], b[t][ni], acc[mi][ni], 0, 0, 0);
                }
        __syncthreads();
    }
    // C/D layout: col = lane&15, row = (lane>>4)*4 + j  [m89-verified]
#pragma unroll
    for (int mi = 0; mi < 4; ++mi)
#pragma unroll
        for (int ni = 0; ni < 4; ++ni)
#pragma unroll
            for (int j = 0; j < 4; ++j)
                C[(long)(bm + wr + mi * 16 + (lane >> 4) * 4 + j) * N + bn + wc + ni * 16 + lr] =
                    acc[mi][ni][j];
}

// ---------------- sub-GCN: H[n] (+)= Sn @ (Xin[n] @ W) + b ----------------
__global__ __launch_bounds__(256) void gcn_kernel(const float* __restrict__ Xin,
                                                  const float* __restrict__ W,
                                                  const float* __restrict__ bias,
                                                  const float* __restrict__ Sn,
                                                  float* __restrict__ H, int accum) {
    __shared__ float Xs[64][65];
    __shared__ float Ws[64][65];
    __shared__ float Ts[64][65];
    const int n = blockIdx.x;
    const int tid = threadIdx.x;
    const float* Xn = Xin + (size_t)n * MD;
    for (int t = tid; t < 4096; t += 256) {
        int r = t >> 6, c = t & 63;
        Xs[r][c] = Xn[t];
        Ws[r][c] = W[t];
    }
    __syncthreads();
    const int tx = tid & 15, ty = tid >> 4;
    float acc[4][4] = {};
#pragma unroll 8
    for (int k = 0; k < 64; ++k) {
        float a0 = Xs[ty * 4 + 0][k], a1 = Xs[ty * 4 + 1][k];
        float a2 = Xs[ty * 4 + 2][k], a3 = Xs[ty * 4 + 3][k];
        float b0 = Ws[k][tx * 4 + 0], b1 = Ws[k][tx * 4 + 1];
        float b2 = Ws[k][tx * 4 + 2], b3 = Ws[k][tx * 4 + 3];
        acc[0][0] += a0 * b0; acc[0][1] += a0 * b1; acc[0][2] += a0 * b2; acc[0][3] += a0 * b3;
        acc[1][0] += a1 * b0; acc[1][1] += a1 * b1; acc[1][2] += a1 * b2; acc[1][3] += a1 * b3;
        acc[2][0] += a2 * b0; acc[2][1] += a2 * b1; acc[2][2] += a2 * b2; acc[2][3] += a2 * b3;
        acc[3][0] += a3 * b0; acc[3][1] += a3 * b1; acc[3][2] += a3 * b2; acc[3][3] += a3 * b3;
    }
#pragma unroll
    for (int i = 0; i < 4; ++i)
#pragma unroll
        for (int j = 0; j < 4; ++j) Ts[ty * 4 + i][tx * 4 + j] = acc[i][j];
    __syncthreads();
    float acc2[4][4] = {};
#pragma unroll 8
    for (int v = 0; v < 64; ++v) {
        float a0 = Sn[(ty * 4 + 0) * 64 + v], a1 = Sn[(ty * 4 + 1) * 64 + v];
        float a2 = Sn[(ty * 4 + 2) * 64 + v], a3 = Sn[(ty * 4 + 3) * 64 + v];
        float b0 = Ts[v][tx * 4 + 0], b1 = Ts[v][tx * 4 + 1];
        float b2 = Ts[v][tx * 4 + 2], b3 = Ts[v][tx * 4 + 3];
        acc2[0][0] += a0 * b0; acc2[0][1] += a0 * b1; acc2[0][2] += a0 * b2; acc2[0][3] += a0 * b3;
        acc2[1][0] += a1 * b0; acc2[1][1] += a1 * b1; acc2[1][2] += a1 * b2; acc2[1][3] += a1 * b3;
        acc2[2][0] += a2 * b0; acc2[2][1] += a2 * b1; acc2[2][2] += a2 * b2; acc2[2][3] += a2 * b3;
        acc2[3][0] += a3 * b0; acc2[3][1] += a3 * b1; acc2[3][2] += a3 * b2; acc2[3][3] += a3 * b3;
    }
    float* Hn = H + (size_t)n * MD;
#pragma unroll
    for (int i = 0; i < 4; ++i)
#pragma unroll
        for (int j = 0; j < 4; ++j) {
            int idx = (ty * 4 + i) * 64 + tx * 4 + j;
            float val = acc2[i][j] + bias[tx * 4 + j];
            Hn[idx] = accum ? (Hn[idx] + val) : val;
        }
}

// ---------------- LayerNorm over (m,d) + ReLU (in-place safe) ----------------
__global__ __launch_bounds__(256) void ln_relu_kernel(const float* __restrict__ H,
                                                      const float* __restrict__ gamma,
                                                      const float* __restrict__ beta,
                                                      float* __restrict__ X) {
    const int n = blockIdx.x;
    const int tid = threadIdx.x;
    const float* h = H + (size_t)n * MD;
    __shared__ float wsum[4], wsum2[4];
    float s = 0.f;
    for (int t = tid; t < MD; t += 256) s += h[t];
#pragma unroll
    for (int o = 32; o; o >>= 1) s += __shfl_down(s, o);
    if ((tid & 63) == 0) wsum[tid >> 6] = s;
    __syncthreads();
    float mean = (wsum[0] + wsum[1] + wsum[2] + wsum[3]) * (1.f / 4096.f);
    float v2 = 0.f;
    for (int t = tid; t < MD; t += 256) { float d = h[t] - mean; v2 += d * d; }
#pragma unroll
    for (int o = 32; o; o >>= 1) v2 += __shfl_down(v2, o);
    if ((tid & 63) == 0) wsum2[tid >> 6] = v2;
    __syncthreads();
    float var = (wsum2[0] + wsum2[1] + wsum2[2] + wsum2[3]) * (1.f / 4096.f);
    float rstd = 1.f / sqrtf(var + EPS);
    float* xo = X + (size_t)n * MD;
    for (int t = tid; t < MD; t += 256) {
        float val = (h[t] - mean) * rstd * gamma[t] + beta[t];
        xo[t] = val > 0.f ? val : 0.f;
    }
}

// ---------------- readout: out = X(N,4096) @ Wlin(4096,64) + blin ----------------
__global__ __launch_bounds__(256) void readout_kernel(const float* __restrict__ X,
                                                      const float* __restrict__ Wl,
                                                      const float* __restrict__ bl,
                                                      float* __restrict__ out) {
    const int n = blockIdx.x;
    const int o = threadIdx.x & 63, c = threadIdx.x >> 6;
    const float* xn = X + (size_t)n * MD;
    float s = 0.f;
    for (int i = c * 1024; i < (c + 1) * 1024; ++i) s += xn[i] * Wl[(size_t)i * 64 + o];
    __shared__ float red[4][64];
    red[c][o] = s;
    __syncthreads();
    if (c == 0) out[(size_t)n * 64 + o] = red[0][o] + red[1][o] + red[2][o] + red[3][o] + bl[o];
}

extern "C" void kernel_launch(void* const* d_in, const int* in_sizes, int n_in,
                              void* d_out, int out_size, void* d_ws, size_t ws_size,
                              hipStream_t stream) {
    const float* x     = (const float*)d_in[0];
    const int*   sub   = (const int*)d_in[1];
    const int*   adj   = (const int*)d_in[2];
    const float* Wc    = (const float*)d_in[3];
    const float* bc    = (const float*)d_in[4];
    const float* gamma = (const float*)d_in[5];
    const float* beta  = (const float*)d_in[6];
    const float* Wlin  = (const float*)d_in[7];
    const float* blin  = (const float*)d_in[8];
    float* out = (float*)d_out;

    // workspace layout (~166 MB)
    char* w = (char*)d_ws;
    u16* Abf = (u16*)w;  w += (size_t)NN * NN * 2;            // 8 MB
    u16* A2p = (u16*)w;  w += (size_t)2 * NN * NN * 2;        // 16 MB
    u16* A3p = (u16*)w;  w += (size_t)3 * NN * NN * 2;        // 24 MB
    float* Sn = (float*)w; w += (size_t)4096 * 4;
    u16* S = (u16*)w;    w += (size_t)3 * NN * MD * 2;        // 50.3 MB (x split planes, transposed)
    float* Xp = (float*)w; w += (size_t)NN * MD * 4;          // 33.6 MB
    float* H  = (float*)w; w += (size_t)NN * MD * 4;          // 33.6 MB
    // setup-only aliases inside S (used before first split3t):
    u16* ATbf = S;                                            // 8 MB
    float* A2f = (float*)((char*)S + (size_t)NN * NN * 2);    // 16.8 MB
    float* A3f = (float*)((char*)A2f + (size_t)NN * NN * 4);  // 16.8 MB

    // ---- setup: A powers, exact in bf16 splits ----
    aprep_kernel<<<dim3(32, 32), 256, 0, stream>>>(adj, Abf, ATbf);
    sn_kernel<<<1, 256, 0, stream>>>(sub, Sn);
    gemm_pairs<1, 1, 2><<<dim3(16, 16), 256, 0, stream>>>(Abf, 0, ATbf, 0, A2f, NN, NN, NN);
    split_pow_kernel<2><<<(NN * NN + 255) / 256, 256, 0, stream>>>(A2f, A2p, (long)NN * NN);
    gemm_pairs<2, 1, 2><<<dim3(16, 16), 256, 0, stream>>>(A2p, (long)NN * NN, ATbf, 0, A3f, NN, NN, NN);
    split_pow_kernel<3><<<(NN * NN + 255) / 256, 256, 0, stream>>>(A3f, A3p, (long)NN * NN);

    const float* xin = x;
    for (int l = 0; l < NLAYER; ++l) {
        const float* Wl = Wc + (size_t)l * 4 * 4096;
        const float* bl = bc + (size_t)l * 4 * 64;
        split3t_kernel<<<dim3(64, 32), 256, 0, stream>>>(xin, S, NN, MD);
        gcn_kernel<<<NN, 256, 0, stream>>>(xin, Wl, bl, Sn, H, 0);
        gemm_pairs<1, 3, 2><<<dim3(32, 16), 256, 0, stream>>>(Abf, 0, S, (long)NN * MD, Xp, NN, MD, NN);
        gcn_kernel<<<NN, 256, 0, stream>>>(Xp, Wl + 4096, bl + 64, Sn, H, 1);
        split3t_kernel<<<dim3(64, 32), 256, 0, stream>>>(Xp, S, NN, MD);
        gemm_pairs<2, 3, 2><<<dim3(32, 16), 256, 0, stream>>>(A2p, (long)NN * NN, S, (long)NN * MD, Xp, NN, MD, NN);
        gcn_kernel<<<NN, 256, 0, stream>>>(Xp, Wl + 2 * 4096, bl + 2 * 64, Sn, H, 1);
        split3t_kernel<<<dim3(64, 32), 256, 0, stream>>>(Xp, S, NN, MD);
        gemm_pairs<3, 3, 2><<<dim3(32, 16), 256, 0, stream>>>(A3p, (long)NN * NN, S, (long)NN * MD, Xp, NN, MD, NN);
        gcn_kernel<<<NN, 256, 0, stream>>>(Xp, Wl + 3 * 4096, bl + 3 * 64, Sn, H, 1);
        ln_relu_kernel<<<NN, 256, 0, stream>>>(H, gamma + (size_t)l * 4096,
                                               beta + (size_t)l * 4096, H);
        xin = H;
    }
    readout_kernel<<<NN, 256, 0, stream>>>(H, Wlin, blin, out);
}

// Round 4
// 1963.238 us; speedup vs baseline: 3.8262x; 1.1052x over previous
//
#include <hip/hip_runtime.h>
#include <math.h>

// Problem constants
#define NN 2048   // meta-nodes
#define MM 64     // subgraph nodes
#define DD 64     // channels
#define MD 4096   // MM*DD
#define NLAYER 3
#define EPS 1e-5f

typedef unsigned short u16;
typedef unsigned int u32;
typedef __attribute__((ext_vector_type(8))) short bf16x8;
typedef __attribute__((ext_vector_type(4))) float f32x4;

__device__ inline u16 f32_to_bf16(float f) {
    u32 u = __float_as_uint(f);
    u32 r = (u + 0x7FFFu + ((u >> 16) & 1u)) >> 16;   // RNE
    return (u16)r;
}
__device__ inline float bf16_to_f32(u16 h) { return __uint_as_float((u32)h << 16); }
__device__ inline void split3(float f, u16& h, u16& l, u16& q) {
    h = f32_to_bf16(f); float r = f - bf16_to_f32(h);
    l = f32_to_bf16(r); r -= bf16_to_f32(l);
    q = f32_to_bf16(r);
}

// ---------------- A prep: adj(int) -> A bf16 (row-major) + A^T bf16 ----------------
__global__ __launch_bounds__(256) void aprep_kernel(const int* __restrict__ adj,
                                                    u16* __restrict__ Abf,
                                                    u16* __restrict__ ATbf) {
    __shared__ u16 T[64][65];
    const int r0 = blockIdx.y * 64, c0 = blockIdx.x * 64;
    const int tid = threadIdx.x;
#pragma unroll
    for (int e = 0; e < 16; ++e) {
        int idx = e * 256 + tid;
        int i = idx >> 6, j = idx & 63;
        int a = adj[(long)(r0 + i) * NN + c0 + j];
        u16 b = a ? (u16)0x3F80 : (u16)0;
        Abf[(long)(r0 + i) * NN + c0 + j] = b;
        T[i][j] = b;
    }
    __syncthreads();
#pragma unroll
    for (int e = 0; e < 16; ++e) {
        int idx = e * 256 + tid;
        int cc = idx >> 6, rr = idx & 63;
        ATbf[(long)(c0 + cc) * NN + r0 + rr] = T[rr][cc];
    }
}

// ---------------- Sn = D^-1/2 (A+I) D^-1/2, 3-split, swizzled image ----------------
__global__ __launch_bounds__(256) void snprep_kernel(const int* __restrict__ sub,
                                                     u16* __restrict__ SnS) {
    __shared__ float dinv[64];
    __shared__ float Snl[64][65];
    int tid = threadIdx.x;
    if (tid < 64) {
        float s = 1.f;
        for (int v = 0; v < 64; ++v) s += (float)sub[tid * 64 + v];
        dinv[tid] = 1.f / sqrtf(s);
    }
    __syncthreads();
    for (int t = tid; t < 4096; t += 256) {
        int u = t >> 6, v = t & 63;
        float a = (float)sub[t] + (u == v ? 1.f : 0.f);
        Snl[u][v] = dinv[u] * a * dinv[v];
    }
    __syncthreads();
    // 512 16B-units; unit u = row*8 + col/8; image unit = u ^ ((u>>3)&7)
    for (int u = tid * 2; u < tid * 2 + 2; ++u) {
        int row = u >> 3, c8 = u & 7;
        int su = (u ^ ((u >> 3) & 7)) * 8;
#pragma unroll
        for (int e = 0; e < 8; ++e) {
            u16 h, l, q; split3(Snl[row][c8 * 8 + e], h, l, q);
            SnS[su + e] = h;
            SnS[4096 + su + e] = l;
            SnS[8192 + su + e] = q;
        }
    }
}

// ---------------- W prep: [cu][k][d] -> transposed 3-split swizzled images ----------------
__global__ __launch_bounds__(256) void wprep_kernel(const float* __restrict__ Wc,
                                                    u16* __restrict__ WtS) {
    __shared__ float Wl[64][65];
    const int cu = blockIdx.x, tid = threadIdx.x;
    const float* W = Wc + (size_t)cu * 4096;   // [k][d]
    for (int t = tid; t < 4096; t += 256) Wl[t >> 6][t & 63] = W[t];
    __syncthreads();
    u16* dst = WtS + (size_t)cu * 3 * 4096;
    for (int u = tid * 2; u < tid * 2 + 2; ++u) {
        int d = u >> 3, c8 = u & 7;          // Wt row = d, cols k = c8*8+e
        int su = (u ^ ((u >> 3) & 7)) * 8;
#pragma unroll
        for (int e = 0; e < 8; ++e) {
            u16 h, l, q; split3(Wl[c8 * 8 + e][d], h, l, q);
            dst[su + e] = h;
            dst[4096 + su + e] = l;
            dst[8192 + su + e] = q;
        }
    }
}

// ---------------- split fp32 -> S bf16 planes, row-major (for A-powers) ----------------
template <int S>
__global__ __launch_bounds__(256) void split_pow_kernel(const float* __restrict__ X,
                                                        u16* __restrict__ P, long n) {
    long i = (long)blockIdx.x * 256 + threadIdx.x;
    if (i >= n) return;
    float v = X[i];
#pragma unroll
    for (int s = 0; s < S; ++s) {
        u16 h = f32_to_bf16(v);
        P[(long)s * n + i] = h;
        v -= bf16_to_f32(h);
    }
}

// ---------------- split fp32 X[R][C] -> 3 bf16 planes transposed [C][R] ----------------
__global__ __launch_bounds__(256) void split3t_kernel(const float* __restrict__ X,
                                                      u16* __restrict__ P, int R, int Cc) {
    __shared__ float T[64][65];
    const int r0 = blockIdx.y * 64, c0 = blockIdx.x * 64;
    const int tid = threadIdx.x;
#pragma unroll
    for (int e = 0; e < 16; ++e) {
        int idx = e * 256 + tid;
        int i = idx >> 6, j = idx & 63;
        T[i][j] = X[(long)(r0 + i) * Cc + c0 + j];
    }
    __syncthreads();
    const long planeStride = (long)R * Cc;
#pragma unroll
    for (int e = 0; e < 16; ++e) {
        int idx = e * 256 + tid;
        int cc = idx >> 6, rr = idx & 63;
        float v = T[rr][cc];
        u16 h, l, q; split3(v, h, l, q);
        long o = (long)(c0 + cc) * R + r0 + rr;
        P[o] = h;
        P[planeStride + o] = l;
        P[2 * planeStride + o] = q;
    }
}

// ---------------- multi-split-pair MFMA GEMM (staging overlapped with MFMA) ----------------
// C[m][n] = sum_{s<SP,t<SQ,s+t<=SMAX} Ap[s][m][k]*Bp[t][n][k]; BM=BN=128, BK=32.
template <int SP, int SQ, int SMAX>
__global__ __launch_bounds__(256) void gemm_pairs(const u16* __restrict__ Ap, long aStride,
                                                  const u16* __restrict__ Bp, long bStride,
                                                  float* __restrict__ C, int M, int N, int K) {
    __shared__ u16 lds[(SP + SQ) * 4096];
    const int tid = threadIdx.x;
    const int wave = tid >> 6, lane = tid & 63;
    // XCD-aware swizzle (nwg % 8 == 0 for all our grids)
    const int nwg = gridDim.x * gridDim.y;
    int bid = blockIdx.y * gridDim.x + blockIdx.x;
    int sbid = (bid & 7) * (nwg >> 3) + (bid >> 3);
    const int bm = (sbid / gridDim.x) * 128, bn = (sbid % gridDim.x) * 128;
    const int wr = (wave >> 1) * 64, wc = (wave & 1) * 64;

    f32x4 acc[4][4];
#pragma unroll
    for (int i = 0; i < 4; ++i)
#pragma unroll
        for (int j = 0; j < 4; ++j) acc[i][j] = (f32x4){0.f, 0.f, 0.f, 0.f};

    const int kb16 = lane >> 4, lr = lane & 15;
    int aoff[4], boff[4];
#pragma unroll
    for (int mi = 0; mi < 4; ++mi) {
        int ua = (wr + mi * 16 + lr) * 4 + kb16;
        aoff[mi] = (ua ^ ((ua >> 3) & 7)) * 16;
        int ub = (wc + mi * 16 + lr) * 4 + kb16;
        boff[mi] = (ub ^ ((ub >> 3) & 7)) * 16;
    }
    auto stage = [&](int k0) {
#pragma unroll
        for (int u8 = 0; u8 < (SP + SQ) * 2; ++u8) {
            int uu = u8 * 4 + wave;
            int p = uu >> 3, i = uu & 7;
            int us = i * 64 + lane;
            int ulin = us ^ ((us >> 3) & 7);
            int r = ulin >> 2, kb = ulin & 3;
            const u16* src; int rowbase;
            if (p < SP) { src = Ap + (long)p * aStride; rowbase = bm; }
            else        { src = Bp + (long)(p - SP) * bStride; rowbase = bn; }
            const char* g = (const char*)src + ((long)(rowbase + r) * K + k0) * 2 + kb * 16;
            char* l = (char*)lds + p * 8192 + i * 1024 + lane * 16;
            __builtin_amdgcn_global_load_lds((const __attribute__((address_space(1))) void*)g,
                                             (__attribute__((address_space(3))) void*)l, 16, 0, 0);
        }
    };
    stage(0);
    __syncthreads();
    for (int k0 = 0; k0 < K; k0 += 32) {
        bf16x8 a[SP][4], b[SQ][4];
#pragma unroll
        for (int s = 0; s < SP; ++s)
#pragma unroll
            for (int mi = 0; mi < 4; ++mi)
                a[s][mi] = *(const bf16x8*)((const char*)lds + s * 8192 + aoff[mi]);
#pragma unroll
        for (int t = 0; t < SQ; ++t)
#pragma unroll
            for (int ni = 0; ni < 4; ++ni)
                b[t][ni] = *(const bf16x8*)((const char*)lds + (SP + t) * 8192 + boff[ni]);
        __syncthreads();                      // all waves done reading LDS
        if (k0 + 32 < K) stage(k0 + 32);      // overwrite LDS; overlaps with MFMA below
#pragma unroll
        for (int s = 0; s < SP; ++s)
#pragma unroll
            for (int t = 0; t < SQ; ++t)
                if (s + t <= SMAX) {
#pragma unroll
                    for (int mi = 0; mi < 4; ++mi)
#pragma unroll
                        for (int ni = 0; ni < 4; ++ni)
                            acc[mi][ni] = __builtin_amdgcn_mfma_f32_16x16x32_bf16(
                                a[s][mi], b[t][ni], acc[mi][ni], 0, 0, 0);
                }
        __syncthreads();                      // drains vmcnt(0): next tile resident
    }
#pragma unroll
    for (int mi = 0; mi < 4; ++mi)
#pragma unroll
        for (int ni = 0; ni < 4; ++ni)
#pragma unroll
            for (int j = 0; j < 4; ++j)
                C[(long)(bm + wr + mi * 16 + (lane >> 4) * 4 + j) * N + bn + wc + ni * 16 + lr] =
                    acc[mi][ni][j];
}

// ---------------- unified sub-GCN conv kernel (MFMA) ----------------
// Per block = one meta-node n. For c in [0,NC): T^T = Wt_c @ X_c^T (X from global,
// 3-split in regs), Tt via swizzled LDS, accH += Sn @ T + b_c.
// MODE: 0 = H += acc; 1 = H = acc; 2 = H = ReLU(LN(H + acc)); 3 = H = ReLU(LN(acc)).
template <int NC, int MODE>
__global__ __launch_bounds__(256, 2) void gcn_conv_kernel(
    const float* __restrict__ X0, const float* __restrict__ X1,
    const float* __restrict__ X2, const float* __restrict__ X3,
    const u16* __restrict__ WtS,     // [NC][3][4096] swizzled images
    const float* __restrict__ bias,  // [NC][64]
    const u16* __restrict__ SnS,     // [3][4096] swizzled image
    const float* __restrict__ gam, const float* __restrict__ bet,  // [4096] (MODE>=2)
    float* __restrict__ Hout) {
    __shared__ u16 lds[9 * 4096];    // Tt[3] | Wt[3] | Sn[3]
    __shared__ float redf[4];
    const int tid = threadIdx.x;
    const int wave = tid >> 6, lane = tid & 63;
    const int lr = lane & 15, lg = lane >> 4;
    const int n = blockIdx.x;
    const int TT = 0, WT = 3 * 4096, SN = 6 * 4096;  // u16 offsets

    // stage Sn (24KB)
    {
        const char* src = (const char*)SnS;
        char* dst = (char*)lds + (size_t)SN * 2;
#pragma unroll
        for (int i = 0; i < 6; ++i)
            __builtin_amdgcn_global_load_lds(
                (const __attribute__((address_space(1))) void*)(src + (i * 256 + tid) * 16),
                (__attribute__((address_space(3))) void*)(dst + (i * 256 + tid) * 16), 16, 0, 0);
    }
    const float* Xc[4] = {X0, X1, X2, X3};
    f32x4 accH[4];
#pragma unroll
    for (int ni = 0; ni < 4; ++ni) accH[ni] = (f32x4){0.f, 0.f, 0.f, 0.f};

    for (int c = 0; c < NC; ++c) {
        __syncthreads();   // prev conv consumed Tt/Wt; drains outstanding staging
        {
            const char* wsrc = (const char*)(WtS + (size_t)c * 3 * 4096);
            char* wdst = (char*)lds + (size_t)WT * 2;
#pragma unroll
            for (int i = 0; i < 6; ++i)
                __builtin_amdgcn_global_load_lds(
                    (const __attribute__((address_space(1))) void*)(wsrc + (i * 256 + tid) * 16),
                    (__attribute__((address_space(3))) void*)(wdst + (i * 256 + tid) * 16), 16, 0, 0);
        }
        // load X rows (B-operand pattern) and 3-split in registers
        const float* xp = Xc[c] + (size_t)n * 4096;
        bf16x8 xb[3][4][2];
#pragma unroll
        for (int ni = 0; ni < 4; ++ni)
#pragma unroll
            for (int ks = 0; ks < 2; ++ks) {
                int off = (ni * 16 + lr) * 64 + ks * 32 + lg * 8;
                f32x4 v0 = *(const f32x4*)(xp + off);
                f32x4 v1 = *(const f32x4*)(xp + off + 4);
#pragma unroll
                for (int e = 0; e < 8; ++e) {
                    float f = (e < 4) ? v0[e] : v1[e - 4];
                    u16 h, l, q; split3(f, h, l, q);
                    xb[0][ni][ks][e] = (short)h;
                    xb[1][ni][ks][e] = (short)l;
                    xb[2][ni][ks][e] = (short)q;
                }
            }
        __syncthreads();   // Wt staged (barrier drains vmcnt)
        // P1': accT = Wt @ X^T  (rows d = wave band, cols v = subgraph node)
        f32x4 accT[4];
#pragma unroll
        for (int ni = 0; ni < 4; ++ni) accT[ni] = (f32x4){0.f, 0.f, 0.f, 0.f};
#pragma unroll
        for (int ks = 0; ks < 2; ++ks) {
            bf16x8 aw[3];
#pragma unroll
            for (int s = 0; s < 3; ++s) {
                int u = (wave * 16 + lr) * 8 + ks * 4 + lg;
                aw[s] = *(const bf16x8*)(lds + WT + s * 4096 + (u ^ ((u >> 3) & 7)) * 8);
            }
#pragma unroll
            for (int ni = 0; ni < 4; ++ni) {
                accT[ni] = __builtin_amdgcn_mfma_f32_16x16x32_bf16(aw[0], xb[0][ni][ks], accT[ni], 0, 0, 0);
                accT[ni] = __builtin_amdgcn_mfma_f32_16x16x32_bf16(aw[0], xb[1][ni][ks], accT[ni], 0, 0, 0);
                accT[ni] = __builtin_amdgcn_mfma_f32_16x16x32_bf16(aw[1], xb[0][ni][ks], accT[ni], 0, 0, 0);
                accT[ni] = __builtin_amdgcn_mfma_f32_16x16x32_bf16(aw[1], xb[1][ni][ks], accT[ni], 0, 0, 0);
                accT[ni] = __builtin_amdgcn_mfma_f32_16x16x32_bf16(aw[2], xb[0][ni][ks], accT[ni], 0, 0, 0);
                accT[ni] = __builtin_amdgcn_mfma_f32_16x16x32_bf16(aw[0], xb[2][ni][ks], accT[ni], 0, 0, 0);
            }
        }
        // write T^T splits to Tt LDS (row d, col v), swizzled
#pragma unroll
        for (int ni = 0; ni < 4; ++ni)
#pragma unroll
            for (int j = 0; j < 4; ++j) {
                int d = wave * 16 + lg * 4 + j;
                int v = ni * 16 + lr;
                u16 h, l, q; split3(accT[ni][j], h, l, q);
                int u = d * 8 + (v >> 3);
                int o = (u ^ ((u >> 3) & 7)) * 8 + (v & 7);
                lds[TT + o] = h;
                lds[TT + 4096 + o] = l;
                lds[TT + 8192 + o] = q;
            }
        __syncthreads();   // Tt ready
        // P2: accH += Sn @ T  (rows u = wave band, cols d2)
#pragma unroll
        for (int ks = 0; ks < 2; ++ks) {
            bf16x8 as_[3];
#pragma unroll
            for (int s = 0; s < 3; ++s) {
                int u = (wave * 16 + lr) * 8 + ks * 4 + lg;
                as_[s] = *(const bf16x8*)(lds + SN + s * 4096 + (u ^ ((u >> 3) & 7)) * 8);
            }
#pragma unroll
            for (int ni = 0; ni < 4; ++ni) {
                bf16x8 bt[3];
#pragma unroll
                for (int t = 0; t < 3; ++t) {
                    int u = (ni * 16 + lr) * 8 + ks * 4 + lg;
                    bt[t] = *(const bf16x8*)(lds + TT + t * 4096 + (u ^ ((u >> 3) & 7)) * 8);
                }
                accH[ni] = __builtin_amdgcn_mfma_f32_16x16x32_bf16(as_[0], bt[0], accH[ni], 0, 0, 0);
                accH[ni] = __builtin_amdgcn_mfma_f32_16x16x32_bf16(as_[0], bt[1], accH[ni], 0, 0, 0);
                accH[ni] = __builtin_amdgcn_mfma_f32_16x16x32_bf16(as_[1], bt[0], accH[ni], 0, 0, 0);
                accH[ni] = __builtin_amdgcn_mfma_f32_16x16x32_bf16(as_[1], bt[1], accH[ni], 0, 0, 0);
                accH[ni] = __builtin_amdgcn_mfma_f32_16x16x32_bf16(as_[2], bt[0], accH[ni], 0, 0, 0);
                accH[ni] = __builtin_amdgcn_mfma_f32_16x16x32_bf16(as_[0], bt[2], accH[ni], 0, 0, 0);
            }
        }
#pragma unroll
        for (int ni = 0; ni < 4; ++ni) {
            float bv = bias[c * 64 + ni * 16 + lr];
            accH[ni][0] += bv; accH[ni][1] += bv; accH[ni][2] += bv; accH[ni][3] += bv;
        }
    }
    // ---- epilogue ----
    float* hp = Hout + (size_t)n * 4096;
    float val[4][4];
#pragma unroll
    for (int ni = 0; ni < 4; ++ni)
#pragma unroll
        for (int j = 0; j < 4; ++j) {
            int idx = (wave * 16 + lg * 4 + j) * 64 + ni * 16 + lr;
            float v = accH[ni][j];
            if (MODE == 0 || MODE == 2) v += hp[idx];
            val[ni][j] = v;
        }
    if (MODE == 0 || MODE == 1) {
#pragma unroll
        for (int ni = 0; ni < 4; ++ni)
#pragma unroll
            for (int j = 0; j < 4; ++j)
                hp[(wave * 16 + lg * 4 + j) * 64 + ni * 16 + lr] = val[ni][j];
        return;
    }
    // LayerNorm over the 64x64 block + ReLU, in registers
    float part = 0.f;
#pragma unroll
    for (int ni = 0; ni < 4; ++ni)
#pragma unroll
        for (int j = 0; j < 4; ++j) part += val[ni][j];
#pragma unroll
    for (int o = 32; o; o >>= 1) part += __shfl_down(part, o);
    if (lane == 0) redf[wave] = part;
    __syncthreads();
    float mean = (redf[0] + redf[1] + redf[2] + redf[3]) * (1.f / 4096.f);
    float p2 = 0.f;
#pragma unroll
    for (int ni = 0; ni < 4; ++ni)
#pragma unroll
        for (int j = 0; j < 4; ++j) {
            float d_ = val[ni][j] - mean;
            p2 += d_ * d_;
        }
#pragma unroll
    for (int o = 32; o; o >>= 1) p2 += __shfl_down(p2, o);
    __syncthreads();   // everyone has read redf for mean
    if (lane == 0) redf[wave] = p2;
    __syncthreads();
    float var = (redf[0] + redf[1] + redf[2] + redf[3]) * (1.f / 4096.f);
    float rstd = 1.f / sqrtf(var + EPS);
#pragma unroll
    for (int ni = 0; ni < 4; ++ni)
#pragma unroll
        for (int j = 0; j < 4; ++j) {
            int idx = (wave * 16 + lg * 4 + j) * 64 + ni * 16 + lr;
            float v = (val[ni][j] - mean) * rstd * gam[idx] + bet[idx];
            hp[idx] = v > 0.f ? v : 0.f;
        }
}

// ---------------- readout: out = X(N,4096) @ Wlin(4096,64) + blin ----------------
__global__ __launch_bounds__(256) void readout_kernel(const float* __restrict__ X,
                                                      const float* __restrict__ Wl,
                                                      const float* __restrict__ bl,
                                                      float* __restrict__ out) {
    const int n = blockIdx.x;
    const int o = threadIdx.x & 63, c = threadIdx.x >> 6;
    const float* xn = X + (size_t)n * MD;
    float s = 0.f;
    for (int i = c * 1024; i < (c + 1) * 1024; ++i) s += xn[i] * Wl[(size_t)i * 64 + o];
    __shared__ float red[4][64];
    red[c][o] = s;
    __syncthreads();
    if (c == 0) out[(size_t)n * 64 + o] = red[0][o] + red[1][o] + red[2][o] + red[3][o] + bl[o];
}

extern "C" void kernel_launch(void* const* d_in, const int* in_sizes, int n_in,
                              void* d_out, int out_size, void* d_ws, size_t ws_size,
                              hipStream_t stream) {
    const float* x     = (const float*)d_in[0];
    const int*   sub   = (const int*)d_in[1];
    const int*   adj   = (const int*)d_in[2];
    const float* Wc    = (const float*)d_in[3];
    const float* bc    = (const float*)d_in[4];
    const float* gamma = (const float*)d_in[5];
    const float* beta  = (const float*)d_in[6];
    const float* Wlin  = (const float*)d_in[7];
    const float* blin  = (const float*)d_in[8];
    float* out = (float*)d_out;

    // common workspace layout
    char* w = (char*)d_ws;
    u16* Abf = (u16*)w;  w += (size_t)NN * NN * 2;            // 8.4 MB
    u16* A2p = (u16*)w;  w += (size_t)2 * NN * NN * 2;        // 16.8 MB
    u16* A3p = (u16*)w;  w += (size_t)3 * NN * NN * 2;        // 25.2 MB
    u16* SnS = (u16*)w;  w += (size_t)3 * 4096 * 2;
    u16* WtS = (u16*)w;  w += (size_t)12 * 3 * 4096 * 2;      // 288 KB
    u16* S   = (u16*)w;  w += (size_t)3 * NN * MD * 2;        // 50.3 MB
    const size_t baseBytes = (size_t)(w - (char*)d_ws);
    const size_t ybytes = (size_t)NN * MD * 4;                // 33.6 MB
    const bool fused = ws_size >= baseBytes + 4 * ybytes;     // ~235.5 MB needed
    // setup-only aliases inside S:
    u16* ATbf = S;
    float* A2f = (float*)((char*)S + (size_t)NN * NN * 2);
    float* A3f = (float*)((char*)A2f + (size_t)NN * NN * 4);

    // ---- setup: A powers (exact), Sn / W split images ----
    aprep_kernel<<<dim3(32, 32), 256, 0, stream>>>(adj, Abf, ATbf);
    snprep_kernel<<<1, 256, 0, stream>>>(sub, SnS);
    wprep_kernel<<<12, 256, 0, stream>>>(Wc, WtS);
    gemm_pairs<1, 1, 2><<<dim3(16, 16), 256, 0, stream>>>(Abf, 0, ATbf, 0, A2f, NN, NN, NN);
    split_pow_kernel<2><<<(NN * NN + 255) / 256, 256, 0, stream>>>(A2f, A2p, (long)NN * NN);
    gemm_pairs<2, 1, 2><<<dim3(16, 16), 256, 0, stream>>>(A2p, (long)NN * NN, ATbf, 0, A3f, NN, NN, NN);
    split_pow_kernel<3><<<(NN * NN + 255) / 256, 256, 0, stream>>>(A3f, A3p, (long)NN * NN);

    const dim3 gp(32, 16);
    if (fused) {
        float* Y[4];
        for (int i = 0; i < 4; ++i) { Y[i] = (float*)w; w += ybytes; }
        const float* xin = x;
        for (int l = 0; l < NLAYER; ++l) {
            float* p1 = Y[l % 4];
            float* p2 = Y[(l + 1) % 4];
            float* p3 = Y[(l + 2) % 4];
            const u16* Wl = WtS + (size_t)l * 12 * 4096;
            split3t_kernel<<<dim3(64, 32), 256, 0, stream>>>(xin, S, NN, MD);
            gemm_pairs<1, 3, 2><<<gp, 256, 0, stream>>>(Abf, 0, S, (long)NN * MD, p1, NN, MD, NN);
            split3t_kernel<<<dim3(64, 32), 256, 0, stream>>>(p1, S, NN, MD);
            gemm_pairs<2, 3, 2><<<gp, 256, 0, stream>>>(A2p, (long)NN * NN, S, (long)NN * MD, p2, NN, MD, NN);
            split3t_kernel<<<dim3(64, 32), 256, 0, stream>>>(p2, S, NN, MD);
            gemm_pairs<3, 3, 2><<<gp, 256, 0, stream>>>(A3p, (long)NN * NN, S, (long)NN * MD, p3, NN, MD, NN);
            gcn_conv_kernel<4, 3><<<NN, 256, 0, stream>>>(xin, p1, p2, p3, Wl,
                bc + (size_t)l * 256, SnS, gamma + (size_t)l * 4096, beta + (size_t)l * 4096, p1);
            xin = p1;
        }
        readout_kernel<<<NN, 256, 0, stream>>>(xin, Wlin, blin, out);
    } else {
        float* Xp = (float*)w; w += ybytes;
        float* H  = (float*)w; w += ybytes;
        const float* xin = x;
        for (int l = 0; l < NLAYER; ++l) {
            const u16* Wl = WtS + (size_t)l * 12 * 4096;
            const float* bl = bc + (size_t)l * 256;
            split3t_kernel<<<dim3(64, 32), 256, 0, stream>>>(xin, S, NN, MD);
            gemm_pairs<1, 3, 2><<<gp, 256, 0, stream>>>(Abf, 0, S, (long)NN * MD, Xp, NN, MD, NN);
            gcn_conv_kernel<1, 1><<<NN, 256, 0, stream>>>(xin, xin, xin, xin, Wl, bl,
                SnS, nullptr, nullptr, H);
            gcn_conv_kernel<1, 0><<<NN, 256, 0, stream>>>(Xp, Xp, Xp, Xp, Wl + 3 * 4096, bl + 64,
                SnS, nullptr, nullptr, H);
            split3t_kernel<<<dim3(64, 32), 256, 0, stream>>>(Xp, S, NN, MD);
            gemm_pairs<2, 3, 2><<<gp, 256, 0, stream>>>(A2p, (long)NN * NN, S, (long)NN * MD, Xp, NN, MD, NN);
            gcn_conv_kernel<1, 0><<<NN, 256, 0, stream>>>(Xp, Xp, Xp, Xp, Wl + 6 * 4096, bl + 128,
                SnS, nullptr, nullptr, H);
            split3t_kernel<<<dim3(64, 32), 256, 0, stream>>>(Xp, S, NN, MD);
            gemm_pairs<3, 3, 2><<<gp, 256, 0, stream>>>(A3p, (long)NN * NN, S, (long)NN * MD, Xp, NN, MD, NN);
            gcn_conv_kernel<1, 2><<<NN, 256, 0, stream>>>(Xp, Xp, Xp, Xp, Wl + 9 * 4096, bl + 192,
                SnS, gamma + (size_t)l * 4096, beta + (size_t)l * 4096, H);
            xin = H;
        }
        readout_kernel<<<NN, 256, 0, stream>>>(xin, Wlin, blin, out);
    }
}

// Round 5
// 1924.559 us; speedup vs baseline: 3.9030x; 1.0201x over previous
//
#include <hip/hip_runtime.h>
#include <math.h>

// Problem constants
#define NN 2048   // meta-nodes
#define MM 64     // subgraph nodes
#define DD 64     // channels
#define MD 4096   // MM*DD
#define NLAYER 3
#define EPS 1e-5f

typedef unsigned short u16;
typedef unsigned int u32;
typedef unsigned long long u64;
typedef __attribute__((ext_vector_type(8))) short bf16x8;
typedef __attribute__((ext_vector_type(4))) float f32x4;

__device__ inline u16 f32_to_bf16(float f) {
    u32 u = __float_as_uint(f);
    u32 r = (u + 0x7FFFu + ((u >> 16) & 1u)) >> 16;   // RNE
    return (u16)r;
}
__device__ inline float bf16_to_f32(u16 h) { return __uint_as_float((u32)h << 16); }
__device__ inline void split3(float f, u16& h, u16& l, u16& q) {
    h = f32_to_bf16(f); float r = f - bf16_to_f32(h);
    l = f32_to_bf16(r); r -= bf16_to_f32(l);
    q = f32_to_bf16(r);
}

// ---------------- A prep: adj(int) -> A bf16 (row-major) + A^T bf16 ----------------
__global__ __launch_bounds__(256) void aprep_kernel(const int* __restrict__ adj,
                                                    u16* __restrict__ Abf,
                                                    u16* __restrict__ ATbf) {
    __shared__ u16 T[64][65];
    const int r0 = blockIdx.y * 64, c0 = blockIdx.x * 64;
    const int tid = threadIdx.x;
#pragma unroll
    for (int e = 0; e < 16; ++e) {
        int idx = e * 256 + tid;
        int i = idx >> 6, j = idx & 63;
        int a = adj[(long)(r0 + i) * NN + c0 + j];
        u16 b = a ? (u16)0x3F80 : (u16)0;
        Abf[(long)(r0 + i) * NN + c0 + j] = b;
        T[i][j] = b;
    }
    __syncthreads();
#pragma unroll
    for (int e = 0; e < 16; ++e) {
        int idx = e * 256 + tid;
        int cc = idx >> 6, rr = idx & 63;
        ATbf[(long)(c0 + cc) * NN + r0 + rr] = T[rr][cc];
    }
}

// ---------------- Sn = D^-1/2 (A+I) D^-1/2, 3-split, swizzled image ----------------
__global__ __launch_bounds__(256) void snprep_kernel(const int* __restrict__ sub,
                                                     u16* __restrict__ SnS) {
    __shared__ float dinv[64];
    __shared__ float Snl[64][65];
    int tid = threadIdx.x;
    if (tid < 64) {
        float s = 1.f;
        for (int v = 0; v < 64; ++v) s += (float)sub[tid * 64 + v];
        dinv[tid] = 1.f / sqrtf(s);
    }
    __syncthreads();
    for (int t = tid; t < 4096; t += 256) {
        int u = t >> 6, v = t & 63;
        float a = (float)sub[t] + (u == v ? 1.f : 0.f);
        Snl[u][v] = dinv[u] * a * dinv[v];
    }
    __syncthreads();
    for (int u = tid * 2; u < tid * 2 + 2; ++u) {
        int row = u >> 3, c8 = u & 7;
        int su = (u ^ ((u >> 3) & 7)) * 8;
#pragma unroll
        for (int e = 0; e < 8; ++e) {
            u16 h, l, q; split3(Snl[row][c8 * 8 + e], h, l, q);
            SnS[su + e] = h;
            SnS[4096 + su + e] = l;
            SnS[8192 + su + e] = q;
        }
    }
}

// ---------------- W prep: [cu][k][d] -> transposed 3-split swizzled images ----------------
__global__ __launch_bounds__(256) void wprep_kernel(const float* __restrict__ Wc,
                                                    u16* __restrict__ WtS) {
    __shared__ float Wl[64][65];
    const int cu = blockIdx.x, tid = threadIdx.x;
    const float* W = Wc + (size_t)cu * 4096;   // [k][d]
    for (int t = tid; t < 4096; t += 256) Wl[t >> 6][t & 63] = W[t];
    __syncthreads();
    u16* dst = WtS + (size_t)cu * 3 * 4096;
    for (int u = tid * 2; u < tid * 2 + 2; ++u) {
        int d = u >> 3, c8 = u & 7;
        int su = (u ^ ((u >> 3) & 7)) * 8;
#pragma unroll
        for (int e = 0; e < 8; ++e) {
            u16 h, l, q; split3(Wl[c8 * 8 + e][d], h, l, q);
            dst[su + e] = h;
            dst[4096 + su + e] = l;
            dst[8192 + su + e] = q;
        }
    }
}

// ---------------- split fp32 X[R][C] -> 3 bf16 planes transposed [C][R] ----------------
__global__ __launch_bounds__(256) void split3t_kernel(const float* __restrict__ X,
                                                      u16* __restrict__ P, int R, int Cc) {
    __shared__ float T[64][65];
    const int r0 = blockIdx.y * 64, c0 = blockIdx.x * 64;
    const int tid = threadIdx.x;
#pragma unroll
    for (int e = 0; e < 16; ++e) {
        int idx = e * 256 + tid;
        int i = idx >> 6, j = idx & 63;
        T[i][j] = X[(long)(r0 + i) * Cc + c0 + j];
    }
    __syncthreads();
    const long planeStride = (long)R * Cc;
#pragma unroll
    for (int e = 0; e < 16; ++e) {
        int idx = e * 256 + tid;
        int cc = idx >> 6, rr = idx & 63;
        float v = T[rr][cc];
        u16 h, l, q; split3(v, h, l, q);
        long o = (long)(c0 + cc) * R + r0 + rr;
        P[o] = h;
        P[planeStride + o] = l;
        P[2 * planeStride + o] = q;
    }
}

// ---------------- multi-split-pair MFMA GEMM, optional fused split-output ----------------
// C[m][n] = sum_{s<SP,t<SQ,s+t<=SMAX} Ap[s][m][k]*Bp[t][n][k]; BM=BN=128, BK=32.
// OSPL = number of split planes also emitted (0 = none).
// OTRANS=1: Sout[t][n][m] (transposed, feeds next gemm's B);  OTRANS=0: Sout[t][m][n].
template <int SP, int SQ, int SMAX, int OSPL, int OTRANS>
__global__ __launch_bounds__(256) void gemm_pairs(const u16* __restrict__ Ap, long aStride,
                                                  const u16* __restrict__ Bp, long bStride,
                                                  float* __restrict__ C,
                                                  u16* __restrict__ Sout,
                                                  int M, int N, int K) {
    __shared__ u16 lds[(SP + SQ) * 4096];
    const int tid = threadIdx.x;
    const int wave = tid >> 6, lane = tid & 63;
    // XCD-aware swizzle (nwg % 8 == 0 for all our grids)
    const int nwg = gridDim.x * gridDim.y;
    int bid = blockIdx.y * gridDim.x + blockIdx.x;
    int sbid = (bid & 7) * (nwg >> 3) + (bid >> 3);
    const int bm = (sbid / gridDim.x) * 128, bn = (sbid % gridDim.x) * 128;
    const int wr = (wave >> 1) * 64, wc = (wave & 1) * 64;

    f32x4 acc[4][4];
#pragma unroll
    for (int i = 0; i < 4; ++i)
#pragma unroll
        for (int j = 0; j < 4; ++j) acc[i][j] = (f32x4){0.f, 0.f, 0.f, 0.f};

    const int kb16 = lane >> 4, lr = lane & 15;
    const int lg = lane >> 4;
    int aoff[4], boff[4];
#pragma unroll
    for (int mi = 0; mi < 4; ++mi) {
        int ua = (wr + mi * 16 + lr) * 4 + kb16;
        aoff[mi] = (ua ^ ((ua >> 3) & 7)) * 16;
        int ub = (wc + mi * 16 + lr) * 4 + kb16;
        boff[mi] = (ub ^ ((ub >> 3) & 7)) * 16;
    }
    auto stage = [&](int k0) {
#pragma unroll
        for (int u8 = 0; u8 < (SP + SQ) * 2; ++u8) {
            int uu = u8 * 4 + wave;
            int p = uu >> 3, i = uu & 7;
            int us = i * 64 + lane;
            int ulin = us ^ ((us >> 3) & 7);
            int r = ulin >> 2, kb = ulin & 3;
            const u16* src; int rowbase;
            if (p < SP) { src = Ap + (long)p * aStride; rowbase = bm; }
            else        { src = Bp + (long)(p - SP) * bStride; rowbase = bn; }
            const char* g = (const char*)src + ((long)(rowbase + r) * K + k0) * 2 + kb * 16;
            char* l = (char*)lds + p * 8192 + i * 1024 + lane * 16;
            __builtin_amdgcn_global_load_lds((const __attribute__((address_space(1))) void*)g,
                                             (__attribute__((address_space(3))) void*)l, 16, 0, 0);
        }
    };
    stage(0);
    __syncthreads();
    for (int k0 = 0; k0 < K; k0 += 32) {
        bf16x8 a[SP][4], b[SQ][4];
#pragma unroll
        for (int s = 0; s < SP; ++s)
#pragma unroll
            for (int mi = 0; mi < 4; ++mi)
                a[s][mi] = *(const bf16x8*)((const char*)lds + s * 8192 + aoff[mi]);
#pragma unroll
        for (int t = 0; t < SQ; ++t)
#pragma unroll
            for (int ni = 0; ni < 4; ++ni)
                b[t][ni] = *(const bf16x8*)((const char*)lds + (SP + t) * 8192 + boff[ni]);
        __syncthreads();                      // all waves done reading LDS
        if (k0 + 32 < K) stage(k0 + 32);      // overwrite LDS; overlaps with MFMA below
#pragma unroll
        for (int s = 0; s < SP; ++s)
#pragma unroll
            for (int t = 0; t < SQ; ++t)
                if (s + t <= SMAX) {
#pragma unroll
                    for (int mi = 0; mi < 4; ++mi)
#pragma unroll
                        for (int ni = 0; ni < 4; ++ni)
                            acc[mi][ni] = __builtin_amdgcn_mfma_f32_16x16x32_bf16(
                                a[s][mi], b[t][ni], acc[mi][ni], 0, 0, 0);
                }
        __syncthreads();                      // drains vmcnt(0): next tile resident
    }
    // fp32 C write.  C/D layout: col = lane&15, row = (lane>>4)*4 + j  [m89]
#pragma unroll
    for (int mi = 0; mi < 4; ++mi)
#pragma unroll
        for (int ni = 0; ni < 4; ++ni)
#pragma unroll
            for (int j = 0; j < 4; ++j)
                C[(long)(bm + wr + mi * 16 + lg * 4 + j) * N + bn + wc + ni * 16 + lr] =
                    acc[mi][ni][j];
    if (OSPL > 0) {
        const long pe = (long)M * N;   // plane elements
        if (OTRANS) {
            // Sout[t][n][m]: pack 4 consecutive-m u16 into one 8B store
#pragma unroll
            for (int ni = 0; ni < 4; ++ni) {
                long col = bn + wc + ni * 16 + lr;
#pragma unroll
                for (int mi = 0; mi < 4; ++mi) {
                    long row0 = bm + wr + mi * 16 + lg * 4;
                    u16 hh[4], ll[4], qq[4];
#pragma unroll
                    for (int j = 0; j < 4; ++j) split3(acc[mi][ni][j], hh[j], ll[j], qq[j]);
                    long o = col * M + row0;
                    *(u64*)(Sout + o) =
                        (u64)hh[0] | ((u64)hh[1] << 16) | ((u64)hh[2] << 32) | ((u64)hh[3] << 48);
                    if (OSPL > 1)
                        *(u64*)(Sout + pe + o) =
                            (u64)ll[0] | ((u64)ll[1] << 16) | ((u64)ll[2] << 32) | ((u64)ll[3] << 48);
                    if (OSPL > 2)
                        *(u64*)(Sout + 2 * pe + o) =
                            (u64)qq[0] | ((u64)qq[1] << 16) | ((u64)qq[2] << 32) | ((u64)qq[3] << 48);
                }
            }
        } else {
            // Sout[t][m][n]: scalar u16, lanes lr contiguous along n
#pragma unroll
            for (int mi = 0; mi < 4; ++mi)
#pragma unroll
                for (int j = 0; j < 4; ++j) {
                    long row = bm + wr + mi * 16 + lg * 4 + j;
#pragma unroll
                    for (int ni = 0; ni < 4; ++ni) {
                        long o = row * N + bn + wc + ni * 16 + lr;
                        u16 h, l, q; split3(acc[mi][ni][j], h, l, q);
                        Sout[o] = h;
                        if (OSPL > 1) Sout[pe + o] = l;
                        if (OSPL > 2) Sout[2 * pe + o] = q;
                    }
                }
        }
    }
}

// ---------------- unified sub-GCN conv kernel (MFMA) — identical to R4 ----------------
// MODE: 0 = H += acc; 1 = H = acc; 2 = H = ReLU(LN(H + acc)); 3 = H = ReLU(LN(acc)).
template <int NC, int MODE>
__global__ __launch_bounds__(256, 2) void gcn_conv_kernel(
    const float* __restrict__ X0, const float* __restrict__ X1,
    const float* __restrict__ X2, const float* __restrict__ X3,
    const u16* __restrict__ WtS,
    const float* __restrict__ bias,
    const u16* __restrict__ SnS,
    const float* __restrict__ gam, const float* __restrict__ bet,
    float* __restrict__ Hout) {
    __shared__ u16 lds[9 * 4096];    // Tt[3] | Wt[3] | Sn[3]
    __shared__ float redf[4];
    const int tid = threadIdx.x;
    const int wave = tid >> 6, lane = tid & 63;
    const int lr = lane & 15, lg = lane >> 4;
    const int n = blockIdx.x;
    const int TT = 0, WT = 3 * 4096, SN = 6 * 4096;

    {
        const char* src = (const char*)SnS;
        char* dst = (char*)lds + (size_t)SN * 2;
#pragma unroll
        for (int i = 0; i < 6; ++i)
            __builtin_amdgcn_global_load_lds(
                (const __attribute__((address_space(1))) void*)(src + (i * 256 + tid) * 16),
                (__attribute__((address_space(3))) void*)(dst + (i * 256 + tid) * 16), 16, 0, 0);
    }
    const float* Xc[4] = {X0, X1, X2, X3};
    f32x4 accH[4];
#pragma unroll
    for (int ni = 0; ni < 4; ++ni) accH[ni] = (f32x4){0.f, 0.f, 0.f, 0.f};

    for (int c = 0; c < NC; ++c) {
        __syncthreads();
        {
            const char* wsrc = (const char*)(WtS + (size_t)c * 3 * 4096);
            char* wdst = (char*)lds + (size_t)WT * 2;
#pragma unroll
            for (int i = 0; i < 6; ++i)
                __builtin_amdgcn_global_load_lds(
                    (const __attribute__((address_space(1))) void*)(wsrc + (i * 256 + tid) * 16),
                    (__attribute__((address_space(3))) void*)(wdst + (i * 256 + tid) * 16), 16, 0, 0);
        }
        const float* xp = Xc[c] + (size_t)n * 4096;
        bf16x8 xb[3][4][2];
#pragma unroll
        for (int ni = 0; ni < 4; ++ni)
#pragma unroll
            for (int ks = 0; ks < 2; ++ks) {
                int off = (ni * 16 + lr) * 64 + ks * 32 + lg * 8;
                f32x4 v0 = *(const f32x4*)(xp + off);
                f32x4 v1 = *(const f32x4*)(xp + off + 4);
#pragma unroll
                for (int e = 0; e < 8; ++e) {
                    float f = (e < 4) ? v0[e] : v1[e - 4];
                    u16 h, l, q; split3(f, h, l, q);
                    xb[0][ni][ks][e] = (short)h;
                    xb[1][ni][ks][e] = (short)l;
                    xb[2][ni][ks][e] = (short)q;
                }
            }
        __syncthreads();
        f32x4 accT[4];
#pragma unroll
        for (int ni = 0; ni < 4; ++ni) accT[ni] = (f32x4){0.f, 0.f, 0.f, 0.f};
#pragma unroll
        for (int ks = 0; ks < 2; ++ks) {
            bf16x8 aw[3];
#pragma unroll
            for (int s = 0; s < 3; ++s) {
                int u = (wave * 16 + lr) * 8 + ks * 4 + lg;
                aw[s] = *(const bf16x8*)(lds + WT + s * 4096 + (u ^ ((u >> 3) & 7)) * 8);
            }
#pragma unroll
            for (int ni = 0; ni < 4; ++ni) {
                accT[ni] = __builtin_amdgcn_mfma_f32_16x16x32_bf16(aw[0], xb[0][ni][ks], accT[ni], 0, 0, 0);
                accT[ni] = __builtin_amdgcn_mfma_f32_16x16x32_bf16(aw[0], xb[1][ni][ks], accT[ni], 0, 0, 0);
                accT[ni] = __builtin_amdgcn_mfma_f32_16x16x32_bf16(aw[1], xb[0][ni][ks], accT[ni], 0, 0, 0);
                accT[ni] = __builtin_amdgcn_mfma_f32_16x16x32_bf16(aw[1], xb[1][ni][ks], accT[ni], 0, 0, 0);
                accT[ni] = __builtin_amdgcn_mfma_f32_16x16x32_bf16(aw[2], xb[0][ni][ks], accT[ni], 0, 0, 0);
                accT[ni] = __builtin_amdgcn_mfma_f32_16x16x32_bf16(aw[0], xb[2][ni][ks], accT[ni], 0, 0, 0);
            }
        }
#pragma unroll
        for (int ni = 0; ni < 4; ++ni)
#pragma unroll
            for (int j = 0; j < 4; ++j) {
                int d = wave * 16 + lg * 4 + j;
                int v = ni * 16 + lr;
                u16 h, l, q; split3(accT[ni][j], h, l, q);
                int u = d * 8 + (v >> 3);
                int o = (u ^ ((u >> 3) & 7)) * 8 + (v & 7);
                lds[TT + o] = h;
                lds[TT + 4096 + o] = l;
                lds[TT + 8192 + o] = q;
            }
        __syncthreads();
#pragma unroll
        for (int ks = 0; ks < 2; ++ks) {
            bf16x8 as_[3];
#pragma unroll
            for (int s = 0; s < 3; ++s) {
                int u = (wave * 16 + lr) * 8 + ks * 4 + lg;
                as_[s] = *(const bf16x8*)(lds + SN + s * 4096 + (u ^ ((u >> 3) & 7)) * 8);
            }
#pragma unroll
            for (int ni = 0; ni < 4; ++ni) {
                bf16x8 bt[3];
#pragma unroll
                for (int t = 0; t < 3; ++t) {
                    int u = (ni * 16 + lr) * 8 + ks * 4 + lg;
                    bt[t] = *(const bf16x8*)(lds + TT + t * 4096 + (u ^ ((u >> 3) & 7)) * 8);
                }
                accH[ni] = __builtin_amdgcn_mfma_f32_16x16x32_bf16(as_[0], bt[0], accH[ni], 0, 0, 0);
                accH[ni] = __builtin_amdgcn_mfma_f32_16x16x32_bf16(as_[0], bt[1], accH[ni], 0, 0, 0);
                accH[ni] = __builtin_amdgcn_mfma_f32_16x16x32_bf16(as_[1], bt[0], accH[ni], 0, 0, 0);
                accH[ni] = __builtin_amdgcn_mfma_f32_16x16x32_bf16(as_[1], bt[1], accH[ni], 0, 0, 0);
                accH[ni] = __builtin_amdgcn_mfma_f32_16x16x32_bf16(as_[2], bt[0], accH[ni], 0, 0, 0);
                accH[ni] = __builtin_amdgcn_mfma_f32_16x16x32_bf16(as_[0], bt[2], accH[ni], 0, 0, 0);
            }
        }
#pragma unroll
        for (int ni = 0; ni < 4; ++ni) {
            float bv = bias[c * 64 + ni * 16 + lr];
            accH[ni][0] += bv; accH[ni][1] += bv; accH[ni][2] += bv; accH[ni][3] += bv;
        }
    }
    float* hp = Hout + (size_t)n * 4096;
    float val[4][4];
#pragma unroll
    for (int ni = 0; ni < 4; ++ni)
#pragma unroll
        for (int j = 0; j < 4; ++j) {
            int idx = (wave * 16 + lg * 4 + j) * 64 + ni * 16 + lr;
            float v = accH[ni][j];
            if (MODE == 0 || MODE == 2) v += hp[idx];
            val[ni][j] = v;
        }
    if (MODE == 0 || MODE == 1) {
#pragma unroll
        for (int ni = 0; ni < 4; ++ni)
#pragma unroll
            for (int j = 0; j < 4; ++j)
                hp[(wave * 16 + lg * 4 + j) * 64 + ni * 16 + lr] = val[ni][j];
        return;
    }
    float part = 0.f;
#pragma unroll
    for (int ni = 0; ni < 4; ++ni)
#pragma unroll
        for (int j = 0; j < 4; ++j) part += val[ni][j];
#pragma unroll
    for (int o = 32; o; o >>= 1) part += __shfl_down(part, o);
    if (lane == 0) redf[wave] = part;
    __syncthreads();
    float mean = (redf[0] + redf[1] + redf[2] + redf[3]) * (1.f / 4096.f);
    float p2 = 0.f;
#pragma unroll
    for (int ni = 0; ni < 4; ++ni)
#pragma unroll
        for (int j = 0; j < 4; ++j) {
            float d_ = val[ni][j] - mean;
            p2 += d_ * d_;
        }
#pragma unroll
    for (int o = 32; o; o >>= 1) p2 += __shfl_down(p2, o);
    __syncthreads();
    if (lane == 0) redf[wave] = p2;
    __syncthreads();
    float var = (redf[0] + redf[1] + redf[2] + redf[3]) * (1.f / 4096.f);
    float rstd = 1.f / sqrtf(var + EPS);
#pragma unroll
    for (int ni = 0; ni < 4; ++ni)
#pragma unroll
        for (int j = 0; j < 4; ++j) {
            int idx = (wave * 16 + lg * 4 + j) * 64 + ni * 16 + lr;
            float v = (val[ni][j] - mean) * rstd * gam[idx] + bet[idx];
            hp[idx] = v > 0.f ? v : 0.f;
        }
}

// ---------------- readout v2: 8 rows/block, Wlin tiled through LDS ----------------
__global__ __launch_bounds__(256) void readout_kernel(const float* __restrict__ X,
                                                      const float* __restrict__ Wl,
                                                      const float* __restrict__ bl,
                                                      float* __restrict__ out) {
    __shared__ float Wls[64][64];
    __shared__ float red[4][8][64];
    const int tid = threadIdx.x;
    const int o = tid & 63, c = tid >> 6;
    const int n0 = blockIdx.x * 8;
    float acc[8] = {};
    const int r = tid >> 2, cq = (tid & 3) * 16;
    for (int k0 = 0; k0 < 4096; k0 += 64) {
        __syncthreads();
        const float* wsrc = Wl + (long)(k0 + r) * 64 + cq;
        *(f32x4*)&Wls[r][cq + 0]  = *(const f32x4*)(wsrc + 0);
        *(f32x4*)&Wls[r][cq + 4]  = *(const f32x4*)(wsrc + 4);
        *(f32x4*)&Wls[r][cq + 8]  = *(const f32x4*)(wsrc + 8);
        *(f32x4*)&Wls[r][cq + 12] = *(const f32x4*)(wsrc + 12);
        __syncthreads();
#pragma unroll
        for (int i = 0; i < 8; ++i) {
            const float* xr = X + (long)(n0 + i) * 4096 + k0 + c * 16;
            float s = acc[i];
#pragma unroll
            for (int kk = 0; kk < 16; ++kk) s += xr[kk] * Wls[c * 16 + kk][o];
            acc[i] = s;
        }
    }
#pragma unroll
    for (int i = 0; i < 8; ++i) red[c][i][o] = acc[i];
    __syncthreads();
    if (c == 0) {
#pragma unroll
        for (int i = 0; i < 8; ++i)
            out[(long)(n0 + i) * 64 + o] =
                red[0][i][o] + red[1][i][o] + red[2][i][o] + red[3][i][o] + bl[o];
    }
}

extern "C" void kernel_launch(void* const* d_in, const int* in_sizes, int n_in,
                              void* d_out, int out_size, void* d_ws, size_t ws_size,
                              hipStream_t stream) {
    const float* x     = (const float*)d_in[0];
    const int*   sub   = (const int*)d_in[1];
    const int*   adj   = (const int*)d_in[2];
    const float* Wc    = (const float*)d_in[3];
    const float* bc    = (const float*)d_in[4];
    const float* gamma = (const float*)d_in[5];
    const float* beta  = (const float*)d_in[6];
    const float* Wlin  = (const float*)d_in[7];
    const float* blin  = (const float*)d_in[8];
    float* out = (float*)d_out;

    char* w = (char*)d_ws;
    u16* Abf = (u16*)w;  w += (size_t)NN * NN * 2;            // 8.4 MB
    u16* A2p = (u16*)w;  w += (size_t)2 * NN * NN * 2;        // 16.8 MB
    u16* A3p = (u16*)w;  w += (size_t)3 * NN * NN * 2;        // 25.2 MB
    u16* SnS = (u16*)w;  w += (size_t)3 * 4096 * 2;
    u16* WtS = (u16*)w;  w += (size_t)12 * 3 * 4096 * 2;      // 288 KB
    const size_t baseBytes = (size_t)(w - (char*)d_ws);       // ~50.7 MB
    const size_t sbytes = (size_t)3 * NN * MD * 2;            // 50.3 MB
    const size_t ybytes = (size_t)NN * MD * 4;                // 33.6 MB
    const long sPlane = (long)NN * MD;                        // elems per S plane

    u16* S0 = (u16*)w;
    u16* ATbf = S0;                                           // setup alias (8.4 MB < plane0)

    const size_t needA = baseBytes + 2 * sbytes + 4 * ybytes; // ~285.6 MB
    const size_t needB = baseBytes + 2 * sbytes + 3 * ybytes; // ~252.0 MB
    int tier = (ws_size >= needA) ? 0 : (ws_size >= needB) ? 1 : 2;

    // fp32 scratch for setup C output (any post-S buffer works in every tier)
    float* Cscr = (tier == 2) ? (float*)((char*)S0 + sbytes)
                              : (float*)((char*)S0 + 2 * sbytes);

    // ---- setup: A powers exact, split planes emitted directly by gemm epilogue ----
    aprep_kernel<<<dim3(32, 32), 256, 0, stream>>>(adj, Abf, ATbf);
    snprep_kernel<<<1, 256, 0, stream>>>(sub, SnS);
    wprep_kernel<<<12, 256, 0, stream>>>(Wc, WtS);
    gemm_pairs<1, 1, 2, 2, 0><<<dim3(16, 16), 256, 0, stream>>>(
        Abf, 0, ATbf, 0, Cscr, A2p, NN, NN, NN);
    gemm_pairs<2, 1, 2, 3, 0><<<dim3(16, 16), 256, 0, stream>>>(
        A2p, (long)NN * NN, ATbf, 0, Cscr, A3p, NN, NN, NN);

    const dim3 gp(32, 16);
    if (tier == 0) {
        // fused gcn<4,3> + split-fused gemms + S ping-pong
        u16* S1 = S0 + (size_t)3 * sPlane;
        float* Y[4];
        char* yw = (char*)S1 + sbytes;
        for (int i = 0; i < 4; ++i) { Y[i] = (float*)yw; yw += ybytes; }
        const float* xin = x;
        for (int l = 0; l < NLAYER; ++l) {
            float* p1 = Y[l % 4];
            float* p2 = Y[(l + 1) % 4];
            float* p3 = Y[(l + 2) % 4];
            const u16* Wl = WtS + (size_t)l * 12 * 4096;
            split3t_kernel<<<dim3(64, 32), 256, 0, stream>>>(xin, S0, NN, MD);
            gemm_pairs<1, 3, 2, 3, 1><<<gp, 256, 0, stream>>>(
                Abf, 0, S0, sPlane, p1, S1, NN, MD, NN);
            gemm_pairs<2, 3, 2, 3, 1><<<gp, 256, 0, stream>>>(
                A2p, (long)NN * NN, S1, sPlane, p2, S0, NN, MD, NN);
            gemm_pairs<3, 3, 2, 0, 0><<<gp, 256, 0, stream>>>(
                A3p, (long)NN * NN, S0, sPlane, p3, nullptr, NN, MD, NN);
            gcn_conv_kernel<4, 3><<<NN, 256, 0, stream>>>(xin, p1, p2, p3, Wl,
                bc + (size_t)l * 256, SnS, gamma + (size_t)l * 4096, beta + (size_t)l * 4096, p1);
            xin = p1;
        }
        readout_kernel<<<NN / 8, 256, 0, stream>>>(xin, Wlin, blin, out);
    } else if (tier == 1) {
        // per-conv gcn + split-fused gemms + S ping-pong
        u16* S1 = S0 + (size_t)3 * sPlane;
        char* yw = (char*)S1 + sbytes;
        float* Xa = (float*)yw; yw += ybytes;
        float* Ha = (float*)yw; yw += ybytes;
        float* Hb = (float*)yw; yw += ybytes;
        const float* xin = x;
        for (int l = 0; l < NLAYER; ++l) {
            float* H = (l & 1) ? Hb : Ha;
            const u16* Wl = WtS + (size_t)l * 12 * 4096;
            const float* bl = bc + (size_t)l * 256;
            split3t_kernel<<<dim3(64, 32), 256, 0, stream>>>(xin, S0, NN, MD);
            gcn_conv_kernel<1, 1><<<NN, 256, 0, stream>>>(xin, xin, xin, xin, Wl, bl,
                SnS, nullptr, nullptr, H);
            gemm_pairs<1, 3, 2, 3, 1><<<gp, 256, 0, stream>>>(
                Abf, 0, S0, sPlane, Xa, S1, NN, MD, NN);
            gcn_conv_kernel<1, 0><<<NN, 256, 0, stream>>>(Xa, Xa, Xa, Xa, Wl + 3 * 4096, bl + 64,
                SnS, nullptr, nullptr, H);
            gemm_pairs<2, 3, 2, 3, 1><<<gp, 256, 0, stream>>>(
                A2p, (long)NN * NN, S1, sPlane, Xa, S0, NN, MD, NN);
            gcn_conv_kernel<1, 0><<<NN, 256, 0, stream>>>(Xa, Xa, Xa, Xa, Wl + 6 * 4096, bl + 128,
                SnS, nullptr, nullptr, H);
            gemm_pairs<3, 3, 2, 0, 0><<<gp, 256, 0, stream>>>(
                A3p, (long)NN * NN, S0, sPlane, Xa, nullptr, NN, MD, NN);
            gcn_conv_kernel<1, 2><<<NN, 256, 0, stream>>>(Xa, Xa, Xa, Xa, Wl + 9 * 4096, bl + 192,
                SnS, gamma + (size_t)l * 4096, beta + (size_t)l * 4096, H);
            xin = H;
        }
        readout_kernel<<<NN / 8, 256, 0, stream>>>(xin, Wlin, blin, out);
    } else {
        // R4-proven safe flow: single S, split3t before every gemm, plain gemms
        char* yw = (char*)S0 + sbytes;
        float* Xp = (float*)yw; yw += ybytes;
        float* H  = (float*)yw; yw += ybytes;
        const float* xin = x;
        for (int l = 0; l < NLAYER; ++l) {
            const u16* Wl = WtS + (size_t)l * 12 * 4096;
            const float* bl = bc + (size_t)l * 256;
            split3t_kernel<<<dim3(64, 32), 256, 0, stream>>>(xin, S0, NN, MD);
            gemm_pairs<1, 3, 2, 0, 0><<<gp, 256, 0, stream>>>(
                Abf, 0, S0, sPlane, Xp, nullptr, NN, MD, NN);
            gcn_conv_kernel<1, 1><<<NN, 256, 0, stream>>>(xin, xin, xin, xin, Wl, bl,
                SnS, nullptr, nullptr, H);
            gcn_conv_kernel<1, 0><<<NN, 256, 0, stream>>>(Xp, Xp, Xp, Xp, Wl + 3 * 4096, bl + 64,
                SnS, nullptr, nullptr, H);
            split3t_kernel<<<dim3(64, 32), 256, 0, stream>>>(Xp, S0, NN, MD);
            gemm_pairs<2, 3, 2, 0, 0><<<gp, 256, 0, stream>>>(
                A2p, (long)NN * NN, S0, sPlane, Xp, nullptr, NN, MD, NN);
            gcn_conv_kernel<1, 0><<<NN, 256, 0, stream>>>(Xp, Xp, Xp, Xp, Wl + 6 * 4096, bl + 128,
                SnS, nullptr, nullptr, H);
            split3t_kernel<<<dim3(64, 32), 256, 0, stream>>>(Xp, S0, NN, MD);
            gemm_pairs<3, 3, 2, 0, 0><<<gp, 256, 0, stream>>>(
                A3p, (long)NN * NN, S0, sPlane, Xp, nullptr, NN, MD, NN);
            gcn_conv_kernel<1, 2><<<NN, 256, 0, stream>>>(Xp, Xp, Xp, Xp, Wl + 9 * 4096, bl + 192,
                SnS, gamma + (size_t)l * 4096, beta + (size_t)l * 4096, H);
            xin = H;
        }
        readout_kernel<<<NN / 8, 256, 0, stream>>>(xin, Wlin, blin, out);
    }
}